// Round 9
// baseline (7147.382 us; speedup 1.0000x reference)
//
#include <hip/hip_runtime.h>
#include <math.h>

#define TT 256
#define HH 100
#define GG 400
#define BB 512

// ---- DPP quad-perm helpers (4-lane groups; VALU pipe) ----------------------
#define DPP_ROT1 147   // dest l <- src (l-1)&3 : perm [3,0,1,2]
#define DPP_ROT2 78    // dest l <- src (l-2)&3 : perm [2,3,0,1]
#define DPP_ROT3 57    // dest l <- src (l-3)&3 : perm [1,2,3,0]
#define DPP_XOR1 177   // perm [1,0,3,2]
#define DPP_XOR2 78    // perm [2,3,0,1]
#define DPP_XOR3 27    // perm [3,2,1,0]

template<int CTRL>
__device__ __forceinline__ float dppf(float v) {
    int i = __float_as_int(v);
    int r = __builtin_amdgcn_update_dpp(i, i, CTRL, 0xf, 0xf, false);
    return __int_as_float(r);
}

// raw transcendental ops (1-ulp class; avoids IEEE div expansion)
__device__ __forceinline__ float fexp2(float x) {
    float r; asm("v_exp_f32 %0, %1" : "=v"(r) : "v"(x)); return r;
}
__device__ __forceinline__ float frcp(float x) {
    float r; asm("v_rcp_f32 %0, %1" : "=v"(r) : "v"(x)); return r;
}
#define LOG2E 1.44269504088896f

// LDS-drain-only barrier: keeps global loads/stores in flight
__device__ __forceinline__ void bar_lds() {
    asm volatile("s_waitcnt lgkmcnt(0)" ::: "memory");
    __builtin_amdgcn_s_barrier();
    asm volatile("" ::: "memory");
}

// ============================ recurrence kernel ==============================
// (unchanged from R8 — ~180 us/layer) 512 blocks x 448 threads, 1 row/block,
// 2 blocks/CU; lb(448,3): cap 170 keeps the 100-float Wq in ARCH VGPRs.
template<int LK>
__global__ void __launch_bounds__(448, 3)
lstm_recur(const float* __restrict__ x,        // [B][T][2]   (LK==0)
           const float* __restrict__ pre,      // [T*B][400]  (LK>=1, bias folded)
           const float* __restrict__ Whh,      // [400][100]
           const float* __restrict__ Wih0,     // [400][2]    (LK==0)
           const float* __restrict__ bih,      // [400]       (LK==0)
           const float* __restrict__ bhh,      // [400]       (LK==0)
           const float* __restrict__ head_w,   // [100]
           const float* __restrict__ head_b,   // [1]
           float* __restrict__ hs,             // [B][T][100] (LK<2 out)
           float* __restrict__ out)            // [B]         (LK==2 out)
{
    __shared__ float hbuf[2][4][28];   // [buf][quarter][25 used + 3 pad]

    const int tid = threadIdx.x;
    const int b   = blockIdx.x;        // one batch row per block
    const int u   = tid >> 2, ty = tid & 3;
    const int g   = ty * HH + u;       // own gate row
    const bool on = (tid < GG);

    // Wq[d][k] = Whh[((ty+d)&3)*100 + u][25*ty + k]
    float Wq[4][25];
    float w0a = 0.f, w0b = 0.f, bias = 0.f;
    if (on) {
        #pragma unroll
        for (int d = 0; d < 4; ++d) {
            const float* wrow = Whh + (((ty + d) & 3) * HH + u) * HH + 25 * ty;
            #pragma unroll
            for (int k = 0; k < 25; ++k) Wq[d][k] = wrow[k];
        }
        if (LK == 0) {
            w0a = Wih0[2 * g]; w0b = Wih0[2 * g + 1];
            bias = bih[g] + bhh[g];
        }
    }
    if (tid < 224) (&hbuf[0][0][0])[tid] = 0.f;   // zero both bufs incl. pads
    float c = 0.f;                                // ty==0 lanes own unit u's cell
    const int q_w = u / 25, i_w = u % 25;         // writer position
    __syncthreads();

    // prefetch t=0 input
    float p0 = 0.f;
    float2 xa = {0.f, 0.f};
    if (on) {
        if (LK == 0) xa = *(const float2*)(x + (size_t)b * TT * 2);
        else         p0 = pre[((size_t)0 * BB + b) * GG + g];
    }

    for (int t = 0; t < TT; ++t) {
        const int cur = t & 1, nxt = cur ^ 1;
        if (on) {
            float ext;
            if (LK == 0) ext = bias + w0a * xa.x + w0b * xa.y;
            else         ext = p0;

            // prefetch t+1 (stays in flight across the raw barrier)
            const int tn = (t + 1 < TT) ? t + 1 : t;
            if (LK == 0) xa = *(const float2*)(x + ((size_t)b * TT + tn) * 2);
            else         p0 = pre[((size_t)tn * BB + b) * GG + g];

            const float4* hq = (const float4*)&hbuf[cur][ty][0];

            float pA = 0.f, pB = 0.f, pC = 0.f, pD = 0.f;
            #pragma unroll
            for (int i = 0; i < 6; ++i) {
                const float4 h4 = hq[i];
                pA += Wq[0][4*i+0] * h4.x; pB += Wq[1][4*i+0] * h4.x;
                pC += Wq[2][4*i+0] * h4.x; pD += Wq[3][4*i+0] * h4.x;
                pA += Wq[0][4*i+1] * h4.y; pB += Wq[1][4*i+1] * h4.y;
                pC += Wq[2][4*i+1] * h4.y; pD += Wq[3][4*i+1] * h4.y;
                pA += Wq[0][4*i+2] * h4.z; pB += Wq[1][4*i+2] * h4.z;
                pC += Wq[2][4*i+2] * h4.z; pD += Wq[3][4*i+2] * h4.z;
                pA += Wq[0][4*i+3] * h4.w; pB += Wq[1][4*i+3] * h4.w;
                pC += Wq[2][4*i+3] * h4.w; pD += Wq[3][4*i+3] * h4.w;
            }
            const float hl = hq[6].x;   // k = 24 of the quarter
            pA += Wq[0][24] * hl; pB += Wq[1][24] * hl;
            pC += Wq[2][24] * hl; pD += Wq[3][24] * hl;

            // cross-quad combine: lane j gets gate-j partials from j-1,j-2,j-3
            float tot = pA + dppf<DPP_ROT1>(pB) + dppf<DPP_ROT2>(pC)
                           + dppf<DPP_ROT3>(pD) + ext;

            // activation by own role (ty==2 is the g-gate -> tanh)
            const bool isG = (ty == 2);
            float v = isG ? 2.f * tot : tot;
            float s = frcp(1.f + fexp2(-LOG2E * v));
            if (isG) s = 2.f * s - 1.f;

            // gather the other three activated gates
            float B0 = dppf<DPP_XOR1>(s), C0 = dppf<DPP_XOR2>(s), D0 = dppf<DPP_XOR3>(s);

            if (ty == 0) {   // s=sig(i), B0=sig(f), C0=tanh(g), D0=sig(o)
                c = B0 * c + s * C0;
                float th = 2.f * frcp(1.f + fexp2(-2.f * LOG2E * c)) - 1.f;
                float hv = D0 * th;
                hbuf[nxt][q_w][i_w] = hv;
                if (LK < 2) hs[((size_t)b * TT + t) * HH + u] = hv;
            }
        }
        bar_lds();   // h(t) visible; orders hbuf[cur] reuse at t+1
    }

    // head: final h is in hbuf[0] (t=255 wrote nxt=0)
    if (LK == 2 && tid < 64) {
        const int lane = tid;
        float p = hbuf[0][lane / 25][lane % 25] * head_w[lane];
        if (lane < 36) {
            const int k2 = 64 + lane;
            p += hbuf[0][k2 / 25][k2 % 25] * head_w[k2];
        }
        #pragma unroll
        for (int off = 32; off; off >>= 1) p += __shfl_down(p, off);
        if (lane == 0) out[b] = p + head_b[0];
    }
}

// ============================ x-projection GEMM ==============================
// pre[row][g] = bias[g] + dot(hs_row, Wih[g]), row = t*512+b.
// Register-W design (clean-codegen pattern from R2-gemm/R8-recur):
//  - 1024 blocks x 448 threads (g = tid < 400 active), lb(448,3) cap 170;
//  - thread g holds Wih[g][0..99] in 100 ARCH VGPRs; block owns 128 rows x
//    ALL 400 gates -> hs read exactly once (no tile re-reads);
//  - A rows staged in 32-row LDS tiles; reads are wave-uniform broadcasts
//    (conflict-free); next tile's global loads prefetched to regs and kept
//    in flight across lgkm-only barriers.
__global__ void __launch_bounds__(448, 3)
gemm_pre(const float* __restrict__ hs,     // [B][T][100]
         const float* __restrict__ Wih,    // [400][100]
         const float* __restrict__ bih,    // [400]
         const float* __restrict__ bhh,    // [400]
         float* __restrict__ pre)          // [M][400]
{
    __shared__ float As[32 * 100];         // one 32-row tile, row-major

    const int tid = threadIdx.x;
    const bool on = (tid < GG);
    const int g   = tid;
    const int row0   = blockIdx.x * 128;   // 128 rows, same t (512%128==0)
    const int t      = row0 >> 9;
    const int b_base = row0 & 511;

    // W row -> 100 arch VGPRs; bias folded
    float wih[100];
    float bias = 0.f;
    if (on) {
        const float4* ws = (const float4*)(Wih + (size_t)g * HH);
        #pragma unroll
        for (int q = 0; q < 25; ++q) {
            float4 v = ws[q];
            wih[4*q+0] = v.x; wih[4*q+1] = v.y;
            wih[4*q+2] = v.z; wih[4*q+3] = v.w;
        }
        bias = bih[g] + bhh[g];
    }

    // tile staging: 800 float4 per tile; thread covers L = tid and tid+448
    const int L0 = tid, L1 = tid + 448;
    const int r0 = L0 / 25, k0 = L0 % 25;   // L0 < 800 always (448)
    const int r1 = L1 / 25, k1 = L1 % 25;   // valid if L1 < 800 (tid < 352)

    float4 pa, pb;
    {   // prefetch tile 0
        pa = *(const float4*)(hs + ((size_t)(b_base + r0) * TT + t) * HH + 4 * k0);
        if (L1 < 800)
            pb = *(const float4*)(hs + ((size_t)(b_base + r1) * TT + t) * HH + 4 * k1);
    }

    #pragma unroll
    for (int tile = 0; tile < 4; ++tile) {
        bar_lds();                         // prev compute done -> buf free
        *(float4*)(As + 4 * L0) = pa;      // (compiler waits vmcnt for pa)
        if (L1 < 800) *(float4*)(As + 4 * L1) = pb;

        if (tile < 3) {                    // prefetch next tile; stays in flight
            const int rb = (tile + 1) * 32;
            pa = *(const float4*)(hs + ((size_t)(b_base + rb + r0) * TT + t) * HH + 4 * k0);
            if (L1 < 800)
                pb = *(const float4*)(hs + ((size_t)(b_base + rb + r1) * TT + t) * HH + 4 * k1);
        }
        bar_lds();                         // tile visible (lgkm only)

        if (on) {
            #pragma unroll 4
            for (int r = 0; r < 32; ++r) {
                const float4* ar = (const float4*)(As + 100 * r);  // bcast reads
                float ae = bias, ao = 0.f;
                #pragma unroll
                for (int q = 0; q < 25; ++q) {
                    const float4 a = ar[q];
                    ae += wih[4*q+0] * a.x; ao += wih[4*q+1] * a.y;
                    ae += wih[4*q+2] * a.z; ao += wih[4*q+3] * a.w;
                }
                const size_t row = (size_t)row0 + tile * 32 + r;
                pre[row * GG + g] = ae + ao;
            }
        }
    }
}

// =============================================================================
extern "C" void kernel_launch(void* const* d_in, const int* in_sizes, int n_in,
                              void* d_out, int out_size, void* d_ws, size_t ws_size,
                              hipStream_t stream) {
    const float* x         = (const float*)d_in[0];
    const float* W_ih0     = (const float*)d_in[1];
    const float* W_ih_rest = (const float*)d_in[2];
    const float* W_hh      = (const float*)d_in[3];
    const float* b_ih      = (const float*)d_in[4];
    const float* b_hh      = (const float*)d_in[5];
    const float* head_w    = (const float*)d_in[6];
    const float* head_b    = (const float*)d_in[7];
    float* out = (float*)d_out;

    const size_t HS_BYTES = (size_t)BB * TT * HH * 4;   // 52.4 MB
    float* hs  = (float*)d_ws;
    float* pre = (float*)((char*)d_ws + HS_BYTES);      // 209.7 MB

    lstm_recur<0><<<512, 448, 0, stream>>>(
        x, nullptr, W_hh, W_ih0, b_ih, b_hh, head_w, head_b, hs, out);

    gemm_pre<<<1024, 448, 0, stream>>>(hs, W_ih_rest, b_ih + GG, b_hh + GG, pre);
    lstm_recur<1><<<512, 448, 0, stream>>>(
        nullptr, pre, W_hh + 40000, nullptr, nullptr, nullptr, head_w, head_b, hs, out);

    gemm_pre<<<1024, 448, 0, stream>>>(hs, W_ih_rest + 40000, b_ih + 2*GG, b_hh + 2*GG, pre);
    lstm_recur<2><<<512, 448, 0, stream>>>(
        nullptr, pre, W_hh + 80000, nullptr, nullptr, nullptr, head_w, head_b, hs, out);
}

// Round 10
// 1322.422 us; speedup vs baseline: 5.4048x; 5.4048x over previous
//
#include <hip/hip_runtime.h>
#include <math.h>

#define TT 256
#define HH 100
#define GG 400
#define BB 512

// ---- DPP quad-perm helpers (4-lane groups; VALU pipe) ----------------------
#define DPP_ROT1 147   // dest l <- src (l-1)&3 : perm [3,0,1,2]
#define DPP_ROT2 78    // dest l <- src (l-2)&3 : perm [2,3,0,1]
#define DPP_ROT3 57    // dest l <- src (l-3)&3 : perm [1,2,3,0]
#define DPP_XOR1 177   // perm [1,0,3,2]
#define DPP_XOR2 78    // perm [2,3,0,1]
#define DPP_XOR3 27    // perm [3,2,1,0]

template<int CTRL>
__device__ __forceinline__ float dppf(float v) {
    int i = __float_as_int(v);
    int r = __builtin_amdgcn_update_dpp(i, i, CTRL, 0xf, 0xf, false);
    return __int_as_float(r);
}

// raw transcendental ops (1-ulp class; avoids IEEE div expansion)
__device__ __forceinline__ float fexp2(float x) {
    float r; asm("v_exp_f32 %0, %1" : "=v"(r) : "v"(x)); return r;
}
__device__ __forceinline__ float frcp(float x) {
    float r; asm("v_rcp_f32 %0, %1" : "=v"(r) : "v"(x)); return r;
}
#define LOG2E 1.44269504088896f

// LDS-drain-only barrier: keeps global loads/stores in flight
__device__ __forceinline__ void bar_lds() {
    asm volatile("s_waitcnt lgkmcnt(0)" ::: "memory");
    __builtin_amdgcn_s_barrier();
    asm volatile("" ::: "memory");
}

// ============================ recurrence kernel ==============================
// (unchanged from R8 — ~180 us/layer) 512 blocks x 448 threads, 1 row/block,
// 2 blocks/CU; lb(448,3): cap 170 keeps the 100-float Wq in ARCH VGPRs.
template<int LK>
__global__ void __launch_bounds__(448, 3)
lstm_recur(const float* __restrict__ x,        // [B][T][2]   (LK==0)
           const float* __restrict__ pre,      // [T*B][400]  (LK>=1, bias folded)
           const float* __restrict__ Whh,      // [400][100]
           const float* __restrict__ Wih0,     // [400][2]    (LK==0)
           const float* __restrict__ bih,      // [400]       (LK==0)
           const float* __restrict__ bhh,      // [400]       (LK==0)
           const float* __restrict__ head_w,   // [100]
           const float* __restrict__ head_b,   // [1]
           float* __restrict__ hs,             // [B][T][100] (LK<2 out)
           float* __restrict__ out)            // [B]         (LK==2 out)
{
    __shared__ float hbuf[2][4][28];   // [buf][quarter][25 used + 3 pad]

    const int tid = threadIdx.x;
    const int b   = blockIdx.x;        // one batch row per block
    const int u   = tid >> 2, ty = tid & 3;
    const int g   = ty * HH + u;       // own gate row
    const bool on = (tid < GG);

    // Wq[d][k] = Whh[((ty+d)&3)*100 + u][25*ty + k]
    float Wq[4][25];
    float w0a = 0.f, w0b = 0.f, bias = 0.f;
    if (on) {
        #pragma unroll
        for (int d = 0; d < 4; ++d) {
            const float* wrow = Whh + (((ty + d) & 3) * HH + u) * HH + 25 * ty;
            #pragma unroll
            for (int k = 0; k < 25; ++k) Wq[d][k] = wrow[k];
        }
        if (LK == 0) {
            w0a = Wih0[2 * g]; w0b = Wih0[2 * g + 1];
            bias = bih[g] + bhh[g];
        }
    }
    if (tid < 224) (&hbuf[0][0][0])[tid] = 0.f;   // zero both bufs incl. pads
    float c = 0.f;                                // ty==0 lanes own unit u's cell
    const int q_w = u / 25, i_w = u % 25;         // writer position
    __syncthreads();

    // prefetch t=0 input
    float p0 = 0.f;
    float2 xa = {0.f, 0.f};
    if (on) {
        if (LK == 0) xa = *(const float2*)(x + (size_t)b * TT * 2);
        else         p0 = pre[((size_t)0 * BB + b) * GG + g];
    }

    for (int t = 0; t < TT; ++t) {
        const int cur = t & 1, nxt = cur ^ 1;
        if (on) {
            float ext;
            if (LK == 0) ext = bias + w0a * xa.x + w0b * xa.y;
            else         ext = p0;

            // prefetch t+1 (stays in flight across the raw barrier)
            const int tn = (t + 1 < TT) ? t + 1 : t;
            if (LK == 0) xa = *(const float2*)(x + ((size_t)b * TT + tn) * 2);
            else         p0 = pre[((size_t)tn * BB + b) * GG + g];

            const float4* hq = (const float4*)&hbuf[cur][ty][0];

            float pA = 0.f, pB = 0.f, pC = 0.f, pD = 0.f;
            #pragma unroll
            for (int i = 0; i < 6; ++i) {
                const float4 h4 = hq[i];
                pA += Wq[0][4*i+0] * h4.x; pB += Wq[1][4*i+0] * h4.x;
                pC += Wq[2][4*i+0] * h4.x; pD += Wq[3][4*i+0] * h4.x;
                pA += Wq[0][4*i+1] * h4.y; pB += Wq[1][4*i+1] * h4.y;
                pC += Wq[2][4*i+1] * h4.y; pD += Wq[3][4*i+1] * h4.y;
                pA += Wq[0][4*i+2] * h4.z; pB += Wq[1][4*i+2] * h4.z;
                pC += Wq[2][4*i+2] * h4.z; pD += Wq[3][4*i+2] * h4.z;
                pA += Wq[0][4*i+3] * h4.w; pB += Wq[1][4*i+3] * h4.w;
                pC += Wq[2][4*i+3] * h4.w; pD += Wq[3][4*i+3] * h4.w;
            }
            const float hl = hq[6].x;   // k = 24 of the quarter
            pA += Wq[0][24] * hl; pB += Wq[1][24] * hl;
            pC += Wq[2][24] * hl; pD += Wq[3][24] * hl;

            // cross-quad combine: lane j gets gate-j partials from j-1,j-2,j-3
            float tot = pA + dppf<DPP_ROT1>(pB) + dppf<DPP_ROT2>(pC)
                           + dppf<DPP_ROT3>(pD) + ext;

            // activation by own role (ty==2 is the g-gate -> tanh)
            const bool isG = (ty == 2);
            float v = isG ? 2.f * tot : tot;
            float s = frcp(1.f + fexp2(-LOG2E * v));
            if (isG) s = 2.f * s - 1.f;

            // gather the other three activated gates
            float B0 = dppf<DPP_XOR1>(s), C0 = dppf<DPP_XOR2>(s), D0 = dppf<DPP_XOR3>(s);

            if (ty == 0) {   // s=sig(i), B0=sig(f), C0=tanh(g), D0=sig(o)
                c = B0 * c + s * C0;
                float th = 2.f * frcp(1.f + fexp2(-2.f * LOG2E * c)) - 1.f;
                float hv = D0 * th;
                hbuf[nxt][q_w][i_w] = hv;
                if (LK < 2) hs[((size_t)b * TT + t) * HH + u] = hv;
            }
        }
        bar_lds();   // h(t) visible; orders hbuf[cur] reuse at t+1
    }

    // head: final h is in hbuf[0] (t=255 wrote nxt=0)
    if (LK == 2 && tid < 64) {
        const int lane = tid;
        float p = hbuf[0][lane / 25][lane % 25] * head_w[lane];
        if (lane < 36) {
            const int k2 = 64 + lane;
            p += hbuf[0][k2 / 25][k2 % 25] * head_w[k2];
        }
        #pragma unroll
        for (int off = 32; off; off >>= 1) p += __shfl_down(p, off);
        if (lane == 0) out[b] = p + head_b[0];
    }
}

// ============================ x-projection GEMM ==============================
// pre[row][g] = bias[g] + dot(hs_row, Wih[g]), row = t*512+b.
// Register-W design. lb(448,2): cap 256 — R9's lb(448,3) (cap 170) forced the
// 100-float wih into SCRATCH (VGPR=84, 5.9 GB FETCH, 3.3 ms). R2 precedent:
// same array under cap 256 allocated cleanly (VGPR=108). Inner unroll 2 keeps
// peak pressure <=146 so 2 blocks/CU can still co-reside.
__global__ void __launch_bounds__(448, 2)
gemm_pre(const float* __restrict__ hs,     // [B][T][100]
         const float* __restrict__ Wih,    // [400][100]
         const float* __restrict__ bih,    // [400]
         const float* __restrict__ bhh,    // [400]
         float* __restrict__ pre)          // [M][400]
{
    __shared__ float As[32 * 100];         // one 32-row tile, row-major

    const int tid = threadIdx.x;
    const bool on = (tid < GG);
    const int g   = tid;
    const int row0   = blockIdx.x * 128;   // 128 rows, same t (512%128==0)
    const int t      = row0 >> 9;
    const int b_base = row0 & 511;

    // W row -> 100 arch VGPRs; bias folded
    float wih[100];
    float bias = 0.f;
    if (on) {
        const float4* ws = (const float4*)(Wih + (size_t)g * HH);
        #pragma unroll
        for (int q = 0; q < 25; ++q) {
            float4 v = ws[q];
            wih[4*q+0] = v.x; wih[4*q+1] = v.y;
            wih[4*q+2] = v.z; wih[4*q+3] = v.w;
        }
        bias = bih[g] + bhh[g];
    }

    // tile staging: 800 float4 per tile; thread covers L = tid and tid+448
    const int L0 = tid, L1 = tid + 448;
    const int r0 = L0 / 25, k0 = L0 % 25;   // L0 < 800 always (448)
    const int r1 = L1 / 25, k1 = L1 % 25;   // valid if L1 < 800 (tid < 352)

    float4 pa, pb;
    {   // prefetch tile 0
        pa = *(const float4*)(hs + ((size_t)(b_base + r0) * TT + t) * HH + 4 * k0);
        if (L1 < 800)
            pb = *(const float4*)(hs + ((size_t)(b_base + r1) * TT + t) * HH + 4 * k1);
    }

    #pragma unroll
    for (int tile = 0; tile < 4; ++tile) {
        bar_lds();                         // prev compute done -> buf free
        *(float4*)(As + 4 * L0) = pa;      // (compiler waits vmcnt for pa)
        if (L1 < 800) *(float4*)(As + 4 * L1) = pb;

        if (tile < 3) {                    // prefetch next tile; stays in flight
            const int rb = (tile + 1) * 32;
            pa = *(const float4*)(hs + ((size_t)(b_base + rb + r0) * TT + t) * HH + 4 * k0);
            if (L1 < 800)
                pb = *(const float4*)(hs + ((size_t)(b_base + rb + r1) * TT + t) * HH + 4 * k1);
        }
        bar_lds();                         // tile visible (lgkm only)

        if (on) {
            #pragma unroll 2
            for (int r = 0; r < 32; ++r) {
                const float4* ar = (const float4*)(As + 100 * r);  // bcast reads
                float ae = bias, ao = 0.f;
                #pragma unroll
                for (int q = 0; q < 25; ++q) {
                    const float4 a = ar[q];
                    ae += wih[4*q+0] * a.x; ao += wih[4*q+1] * a.y;
                    ae += wih[4*q+2] * a.z; ao += wih[4*q+3] * a.w;
                }
                const size_t row = (size_t)row0 + tile * 32 + r;
                pre[row * GG + g] = ae + ao;
            }
        }
    }
}

// =============================================================================
extern "C" void kernel_launch(void* const* d_in, const int* in_sizes, int n_in,
                              void* d_out, int out_size, void* d_ws, size_t ws_size,
                              hipStream_t stream) {
    const float* x         = (const float*)d_in[0];
    const float* W_ih0     = (const float*)d_in[1];
    const float* W_ih_rest = (const float*)d_in[2];
    const float* W_hh      = (const float*)d_in[3];
    const float* b_ih      = (const float*)d_in[4];
    const float* b_hh      = (const float*)d_in[5];
    const float* head_w    = (const float*)d_in[6];
    const float* head_b    = (const float*)d_in[7];
    float* out = (float*)d_out;

    const size_t HS_BYTES = (size_t)BB * TT * HH * 4;   // 52.4 MB
    float* hs  = (float*)d_ws;
    float* pre = (float*)((char*)d_ws + HS_BYTES);      // 209.7 MB

    lstm_recur<0><<<512, 448, 0, stream>>>(
        x, nullptr, W_hh, W_ih0, b_ih, b_hh, head_w, head_b, hs, out);

    gemm_pre<<<1024, 448, 0, stream>>>(hs, W_ih_rest, b_ih + GG, b_hh + GG, pre);
    lstm_recur<1><<<512, 448, 0, stream>>>(
        nullptr, pre, W_hh + 40000, nullptr, nullptr, nullptr, head_w, head_b, hs, out);

    gemm_pre<<<1024, 448, 0, stream>>>(hs, W_ih_rest + 40000, b_ih + 2*GG, b_hh + 2*GG, pre);
    lstm_recur<2><<<512, 448, 0, stream>>>(
        nullptr, pre, W_hh + 80000, nullptr, nullptr, nullptr, head_w, head_b, hs, out);
}

// Round 11
// 995.439 us; speedup vs baseline: 7.1801x; 1.3285x over previous
//
#include <hip/hip_runtime.h>
#include <math.h>

#define TT 256
#define HH 100
#define GG 400
#define BB 512

// ---- DPP quad-perm helpers (4-lane groups; VALU pipe) ----------------------
#define DPP_ROT1 147   // dest l <- src (l-1)&3 : perm [3,0,1,2]
#define DPP_ROT2 78    // dest l <- src (l-2)&3 : perm [2,3,0,1]
#define DPP_ROT3 57    // dest l <- src (l-3)&3 : perm [1,2,3,0]
#define DPP_XOR1 177   // perm [1,0,3,2]
#define DPP_XOR2 78    // perm [2,3,0,1]
#define DPP_XOR3 27    // perm [3,2,1,0]

template<int CTRL>
__device__ __forceinline__ float dppf(float v) {
    int i = __float_as_int(v);
    int r = __builtin_amdgcn_update_dpp(i, i, CTRL, 0xf, 0xf, false);
    return __int_as_float(r);
}

// raw transcendental ops (1-ulp class; avoids IEEE div expansion)
__device__ __forceinline__ float fexp2(float x) {
    float r; asm("v_exp_f32 %0, %1" : "=v"(r) : "v"(x)); return r;
}
__device__ __forceinline__ float frcp(float x) {
    float r; asm("v_rcp_f32 %0, %1" : "=v"(r) : "v"(x)); return r;
}
#define LOG2E 1.44269504088896f

// LDS-drain-only barrier: keeps global loads/stores in flight
__device__ __forceinline__ void bar_lds() {
    asm volatile("s_waitcnt lgkmcnt(0)" ::: "memory");
    __builtin_amdgcn_s_barrier();
    asm volatile("" ::: "memory");
}

// ============================ recurrence kernel ==============================
// (unchanged from R8/R10 — ~170 us/layer) 512 blocks x 448 threads, 1 row/blk,
// 2 blocks/CU; lb(448,3): cap 170 keeps the 100-float Wq in ARCH VGPRs.
template<int LK>
__global__ void __launch_bounds__(448, 3)
lstm_recur(const float* __restrict__ x,        // [B][T][2]   (LK==0)
           const float* __restrict__ pre,      // [T*B][400]  (LK>=1, bias folded)
           const float* __restrict__ Whh,      // [400][100]
           const float* __restrict__ Wih0,     // [400][2]    (LK==0)
           const float* __restrict__ bih,      // [400]       (LK==0)
           const float* __restrict__ bhh,      // [400]       (LK==0)
           const float* __restrict__ head_w,   // [100]
           const float* __restrict__ head_b,   // [1]
           float* __restrict__ hs,             // [B][T][100] (LK<2 out)
           float* __restrict__ out)            // [B]         (LK==2 out)
{
    __shared__ float hbuf[2][4][28];   // [buf][quarter][25 used + 3 pad]

    const int tid = threadIdx.x;
    const int b   = blockIdx.x;        // one batch row per block
    const int u   = tid >> 2, ty = tid & 3;
    const int g   = ty * HH + u;       // own gate row
    const bool on = (tid < GG);

    // Wq[d][k] = Whh[((ty+d)&3)*100 + u][25*ty + k]
    float Wq[4][25];
    float w0a = 0.f, w0b = 0.f, bias = 0.f;
    if (on) {
        #pragma unroll
        for (int d = 0; d < 4; ++d) {
            const float* wrow = Whh + (((ty + d) & 3) * HH + u) * HH + 25 * ty;
            #pragma unroll
            for (int k = 0; k < 25; ++k) Wq[d][k] = wrow[k];
        }
        if (LK == 0) {
            w0a = Wih0[2 * g]; w0b = Wih0[2 * g + 1];
            bias = bih[g] + bhh[g];
        }
    }
    if (tid < 224) (&hbuf[0][0][0])[tid] = 0.f;   // zero both bufs incl. pads
    float c = 0.f;                                // ty==0 lanes own unit u's cell
    const int q_w = u / 25, i_w = u % 25;         // writer position
    __syncthreads();

    // prefetch t=0 input
    float p0 = 0.f;
    float2 xa = {0.f, 0.f};
    if (on) {
        if (LK == 0) xa = *(const float2*)(x + (size_t)b * TT * 2);
        else         p0 = pre[((size_t)0 * BB + b) * GG + g];
    }

    for (int t = 0; t < TT; ++t) {
        const int cur = t & 1, nxt = cur ^ 1;
        if (on) {
            float ext;
            if (LK == 0) ext = bias + w0a * xa.x + w0b * xa.y;
            else         ext = p0;

            // prefetch t+1 (stays in flight across the raw barrier)
            const int tn = (t + 1 < TT) ? t + 1 : t;
            if (LK == 0) xa = *(const float2*)(x + ((size_t)b * TT + tn) * 2);
            else         p0 = pre[((size_t)tn * BB + b) * GG + g];

            const float4* hq = (const float4*)&hbuf[cur][ty][0];

            float pA = 0.f, pB = 0.f, pC = 0.f, pD = 0.f;
            #pragma unroll
            for (int i = 0; i < 6; ++i) {
                const float4 h4 = hq[i];
                pA += Wq[0][4*i+0] * h4.x; pB += Wq[1][4*i+0] * h4.x;
                pC += Wq[2][4*i+0] * h4.x; pD += Wq[3][4*i+0] * h4.x;
                pA += Wq[0][4*i+1] * h4.y; pB += Wq[1][4*i+1] * h4.y;
                pC += Wq[2][4*i+1] * h4.y; pD += Wq[3][4*i+1] * h4.y;
                pA += Wq[0][4*i+2] * h4.z; pB += Wq[1][4*i+2] * h4.z;
                pC += Wq[2][4*i+2] * h4.z; pD += Wq[3][4*i+2] * h4.z;
                pA += Wq[0][4*i+3] * h4.w; pB += Wq[1][4*i+3] * h4.w;
                pC += Wq[2][4*i+3] * h4.w; pD += Wq[3][4*i+3] * h4.w;
            }
            const float hl = hq[6].x;   // k = 24 of the quarter
            pA += Wq[0][24] * hl; pB += Wq[1][24] * hl;
            pC += Wq[2][24] * hl; pD += Wq[3][24] * hl;

            // cross-quad combine: lane j gets gate-j partials from j-1,j-2,j-3
            float tot = pA + dppf<DPP_ROT1>(pB) + dppf<DPP_ROT2>(pC)
                           + dppf<DPP_ROT3>(pD) + ext;

            // activation by own role (ty==2 is the g-gate -> tanh)
            const bool isG = (ty == 2);
            float v = isG ? 2.f * tot : tot;
            float s = frcp(1.f + fexp2(-LOG2E * v));
            if (isG) s = 2.f * s - 1.f;

            // gather the other three activated gates
            float B0 = dppf<DPP_XOR1>(s), C0 = dppf<DPP_XOR2>(s), D0 = dppf<DPP_XOR3>(s);

            if (ty == 0) {   // s=sig(i), B0=sig(f), C0=tanh(g), D0=sig(o)
                c = B0 * c + s * C0;
                float th = 2.f * frcp(1.f + fexp2(-2.f * LOG2E * c)) - 1.f;
                float hv = D0 * th;
                hbuf[nxt][q_w][i_w] = hv;
                if (LK < 2) hs[((size_t)b * TT + t) * HH + u] = hv;
            }
        }
        bar_lds();   // h(t) visible; orders hbuf[cur] reuse at t+1
    }

    // head: final h is in hbuf[0] (t=255 wrote nxt=0)
    if (LK == 2 && tid < 64) {
        const int lane = tid;
        float p = hbuf[0][lane / 25][lane % 25] * head_w[lane];
        if (lane < 36) {
            const int k2 = 64 + lane;
            p += hbuf[0][k2 / 25][k2 % 25] * head_w[k2];
        }
        #pragma unroll
        for (int off = 32; off; off >>= 1) p += __shfl_down(p, off);
        if (lane == 0) out[b] = p + head_b[0];
    }
}

// ============================ x-projection GEMM ==============================
// 8x8-fragment tiled GEMM: LDS-BW is the binding pipe (m134: b128 ~12cyc,
// ~85 B/cyc/CU). Frag 8x8 -> 16 b128 per 256 FMA (1:16), ~20.5 MB LDS
// reads/CU/gemm ~= 100us floor vs R10's 1:4 (~448us) and R3's 1:8 (~200us).
// Tile M=128 x N=200, block 400 = 16 ti x 25 tj, grid (1024, 2).
// A_s [k][128] with per-lane XOR swizzle phys_r = r ^ ((kq&7)<<3): fixes the
// 25-way staging-write conflict (XOR varies per lane via kq); reads stay
// conflict-free (in-wave ti spans <=3 values, never 4 apart).
// W_s [k][200] staged gl-inner (consecutive-lane banks). 131.2 KB dynamic LDS.
__global__ void __launch_bounds__(400, 1)
gemm_pre(const float* __restrict__ hs,     // [B][T][100]
         const float* __restrict__ Wih,    // [400][100]
         const float* __restrict__ bih,    // [400]
         const float* __restrict__ bhh,    // [400]
         float* __restrict__ pre)          // [M][400]
{
    extern __shared__ float lds[];
    float* A_s = lds;            // [100][128]  12800 floats
    float* W_s = lds + 12800;    // [100][200]  20000 floats

    const int tid = threadIdx.x;           // 400
    const int ti  = tid / 25;              // 0..15 -> rows 8ti..8ti+7
    const int tj  = tid % 25;              // 0..24 -> gates 8tj..8tj+7
    const int row0   = blockIdx.x * 128;   // same t (512%128==0)
    const int t      = row0 >> 9;
    const int b_base = row0 & 511;
    const int gbase  = blockIdx.y * 200;

    // ---- stage A: coalesced global read, swizzled transpose write ----
    #pragma unroll
    for (int s = 0; s < 8; ++s) {
        const int L  = tid + 400 * s;      // 0..3199
        const int r  = L / 25, kq = L % 25;
        float4 v = *(const float4*)(hs + ((size_t)(b_base + r) * TT + t) * HH + 4 * kq);
        const int ph = r ^ ((kq & 7) << 3);
        A_s[(4*kq+0)*128 + ph] = v.x;
        A_s[(4*kq+1)*128 + ph] = v.y;
        A_s[(4*kq+2)*128 + ph] = v.z;
        A_s[(4*kq+3)*128 + ph] = v.w;
    }
    // ---- stage W: gl-inner (clean LDS write banks; W is tiny/L2-hot) ----
    for (int L = tid; L < 5000; L += 400) {
        const int kq = L / 200, gl = L % 200;
        float4 v = *(const float4*)(Wih + (size_t)(gbase + gl) * HH + 4 * kq);
        W_s[(4*kq+0)*200 + gl] = v.x;
        W_s[(4*kq+1)*200 + gl] = v.y;
        W_s[(4*kq+2)*200 + gl] = v.z;
        W_s[(4*kq+3)*200 + gl] = v.w;
    }
    __syncthreads();

    // ---- bias ----
    float bj[8];
    {
        const float4 a1 = *(const float4*)(bih + gbase + 8 * tj);
        const float4 a2 = *(const float4*)(bih + gbase + 8 * tj + 4);
        const float4 c1 = *(const float4*)(bhh + gbase + 8 * tj);
        const float4 c2 = *(const float4*)(bhh + gbase + 8 * tj + 4);
        bj[0] = a1.x + c1.x; bj[1] = a1.y + c1.y; bj[2] = a1.z + c1.z; bj[3] = a1.w + c1.w;
        bj[4] = a2.x + c2.x; bj[5] = a2.y + c2.y; bj[6] = a2.z + c2.z; bj[7] = a2.w + c2.w;
    }
    float acc[8][8];
    #pragma unroll
    for (int i = 0; i < 8; ++i)
        #pragma unroll
        for (int j = 0; j < 8; ++j) acc[i][j] = bj[j];

    // ---- main loop: 25 k-groups, 8x8 frag ----
    for (int kq = 0; kq < 25; ++kq) {
        const int axo = (8 * ti) ^ ((kq & 7) << 3);   // swizzled row base
        #pragma unroll
        for (int e = 0; e < 4; ++e) {
            const float* Ak = &A_s[(4*kq + e) * 128];
            const float* Wk = &W_s[(4*kq + e) * 200];
            const float4 a0 = *(const float4*)(Ak + axo);
            const float4 a1 = *(const float4*)(Ak + axo + 4);
            const float4 w0 = *(const float4*)(Wk + 8 * tj);
            const float4 w1 = *(const float4*)(Wk + 8 * tj + 4);
            const float av[8] = {a0.x, a0.y, a0.z, a0.w, a1.x, a1.y, a1.z, a1.w};
            const float wv[8] = {w0.x, w0.y, w0.z, w0.w, w1.x, w1.y, w1.z, w1.w};
            #pragma unroll
            for (int i = 0; i < 8; ++i)
                #pragma unroll
                for (int j = 0; j < 8; ++j)
                    acc[i][j] += av[i] * wv[j];
        }
    }

    // ---- store: 8 rows x 2 float4 ----
    #pragma unroll
    for (int i = 0; i < 8; ++i) {
        const size_t row = (size_t)row0 + 8 * ti + i;
        float4 o0, o1;
        o0.x = acc[i][0]; o0.y = acc[i][1]; o0.z = acc[i][2]; o0.w = acc[i][3];
        o1.x = acc[i][4]; o1.y = acc[i][5]; o1.z = acc[i][6]; o1.w = acc[i][7];
        *(float4*)(pre + row * GG + gbase + 8 * tj)     = o0;
        *(float4*)(pre + row * GG + gbase + 8 * tj + 4) = o1;
    }
}

// =============================================================================
extern "C" void kernel_launch(void* const* d_in, const int* in_sizes, int n_in,
                              void* d_out, int out_size, void* d_ws, size_t ws_size,
                              hipStream_t stream) {
    const float* x         = (const float*)d_in[0];
    const float* W_ih0     = (const float*)d_in[1];
    const float* W_ih_rest = (const float*)d_in[2];
    const float* W_hh      = (const float*)d_in[3];
    const float* b_ih      = (const float*)d_in[4];
    const float* b_hh      = (const float*)d_in[5];
    const float* head_w    = (const float*)d_in[6];
    const float* head_b    = (const float*)d_in[7];
    float* out = (float*)d_out;

    const size_t HS_BYTES = (size_t)BB * TT * HH * 4;   // 52.4 MB
    float* hs  = (float*)d_ws;
    float* pre = (float*)((char*)d_ws + HS_BYTES);      // 209.7 MB

    const int gemm_lds = (12800 + 20000) * 4;           // 131,200 B
    hipFuncSetAttribute((const void*)gemm_pre,
                        hipFuncAttributeMaxDynamicSharedMemorySize, gemm_lds);
    dim3 ggrid(1024, 2);

    lstm_recur<0><<<512, 448, 0, stream>>>(
        x, nullptr, W_hh, W_ih0, b_ih, b_hh, head_w, head_b, hs, out);

    gemm_pre<<<ggrid, 400, gemm_lds, stream>>>(hs, W_ih_rest, b_ih + GG, b_hh + GG, pre);
    lstm_recur<1><<<512, 448, 0, stream>>>(
        nullptr, pre, W_hh + 40000, nullptr, nullptr, nullptr, head_w, head_b, hs, out);

    gemm_pre<<<ggrid, 400, gemm_lds, stream>>>(hs, W_ih_rest + 40000, b_ih + 2*GG, b_hh + 2*GG, pre);
    lstm_recur<2><<<512, 448, 0, stream>>>(
        nullptr, pre, W_hh + 80000, nullptr, nullptr, nullptr, head_w, head_b, hs, out);
}